// Round 1
// 90.423 us; speedup vs baseline: 1.0616x; 1.0616x over previous
//
#include <hip/hip_runtime.h>
#include <math.h>

#define BATCH 131072
#define EPS 1e-8f

// ws layout (floats):
// [0..255]        logw (16x16, [j][0]=0)
// [256]           alpha = logdet(L0 + I)
// [512..16959]    S8 table: per hi-mask h (bits 8..15), 8x8 Schur complement (64 floats)
// [17408..17663]  partial logdet per hi-mask h (pivots of vars 8..15)
// [32768..98303]  T table: logdet(L0[S,S]) - alpha for all 65536 masks

// Stage A: 5 blocks x 64 threads. Thread tg in [0,256): hi-mask task.
// tg==256: alpha task (L0+I, full mask, all 16 pivots).
// Block 4 lanes 32..47 (tg 288..303): log-softmax rows of W.
// Each block recomputes L0 into LDS (cheap; A/B/C are 1 KB each, L2-hot).
__global__ __launch_bounds__(64, 1) void stageA_kernel(const float* __restrict__ W,
                                                       const float* __restrict__ A,
                                                       const float* __restrict__ Bm,
                                                       const float* __restrict__ Cm,
                                                       float* __restrict__ ws) {
    __shared__ float sL0[256];
    int lt = threadIdx.x;
    #pragma unroll
    for (int q = 0; q < 4; ++q) {
        int e = lt * 4 + q;
        int i = e >> 4, j = e & 15;
        float s = 0.f;
        #pragma unroll
        for (int k = 0; k < 16; ++k) {
            s += A[k * 16 + i] * A[k * 16 + j];      // (A^T A)[i][j]
            s += Bm[i * 16 + k] * Cm[j * 16 + k]     // (B C^T)[i][j]
               - Cm[i * 16 + k] * Bm[j * 16 + k];    // (C B^T)[i][j]
        }
        if (i == j) s += EPS;
        sL0[e] = s;
    }
    __syncthreads();

    unsigned tg = blockIdx.x * 64u + (unsigned)lt;

    // log-softmax of W rows (block 4, lanes 32..47)
    if (tg >= 288u && tg < 304u) {
        int r = (int)tg - 288;
        float row[15];
        float mx = -1e30f;
        #pragma unroll
        for (int q = 0; q < 15; ++q) { row[q] = W[r * 15 + q]; mx = fmaxf(mx, row[q]); }
        float se = 0.f;
        #pragma unroll
        for (int q = 0; q < 15; ++q) se += expf(row[q] - mx);
        float lse = mx + logf(se);
        ws[r * 16 + 0] = 0.f;
        #pragma unroll
        for (int q = 0; q < 15; ++q) ws[r * 16 + 1 + q] = row[q] - lse;
    }

    if (tg > 256u) return;
    bool isAlpha = (tg == 256u);
    unsigned h = isAlpha ? 0xFFu : tg;

    // Permuted order P = [8..15, 0..7]: eliminate vars 8..15 first.
    // Vars 0..7 are unmasked here (stage B handles their mask bits).
    float a[16][16];
    #pragma unroll
    for (int r = 0; r < 16; ++r) {
        int i = (r < 8) ? (8 + r) : (r - 8);
        bool pi = (i < 8) ? true : (((h >> (i - 8)) & 1u) != 0u);
        #pragma unroll
        for (int c = 0; c < 16; ++c) {
            int j = (c < 8) ? (8 + c) : (c - 8);
            bool pj = (j < 8) ? true : (((h >> (j - 8)) & 1u) != 0u);
            float v = (pi && pj) ? sL0[i * 16 + j] : ((r == c) ? 1.f : 0.f);
            if (isAlpha && r == c) v += 1.f;      // L0 + I
            a[r][c] = v;
        }
    }

    float plog = 0.f;
    #pragma unroll
    for (int k = 0; k < 8; ++k) {
        float piv = a[k][k];
        plog += __logf(fabsf(piv));
        float inv = 1.0f / piv;
        #pragma unroll
        for (int r2 = k + 1; r2 < 16; ++r2) {
            float f = a[r2][k] * inv;
            #pragma unroll
            for (int c2 = k + 1; c2 < 16; ++c2)
                a[r2][c2] = fmaf(-f, a[k][c2], a[r2][c2]);
        }
    }

    if (!isAlpha) {
        // trailing 8x8 block = Schur complement over vars 0..7
        #pragma unroll
        for (int i = 0; i < 8; ++i)
            #pragma unroll
            for (int j = 0; j < 8; ++j)
                ws[512 + h * 64 + i * 8 + j] = a[8 + i][8 + j];
        ws[17408 + h] = plog;
    } else {
        // finish full LU of L0 + I -> alpha
        #pragma unroll
        for (int k = 8; k < 16; ++k) {
            float piv = a[k][k];
            plog += __logf(fabsf(piv));
            float inv = 1.0f / piv;
            #pragma unroll
            for (int r2 = k + 1; r2 < 16; ++r2) {
                float f = a[r2][k] * inv;
                #pragma unroll
                for (int c2 = k + 1; c2 < 16; ++c2)
                    a[r2][c2] = fmaf(-f, a[k][c2], a[r2][c2]);
            }
        }
        ws[256] = plog;
    }
}

// Stage B: 256 blocks (hi-mask) x 256 threads (lo-mask). 8x8 masked LU from the
// Schur complement; 64 floats/thread -> no spill, high ILP.
__global__ __launch_bounds__(256) void stageB_kernel(const float* __restrict__ ws,
                                                     float* __restrict__ T) {
    __shared__ float s8[64];
    __shared__ float sp[2];
    int lt = threadIdx.x;
    int b  = blockIdx.x;
    if (lt < 64)  s8[lt] = ws[512 + b * 64 + lt];
    if (lt == 64) sp[0] = ws[17408 + b];
    if (lt == 65) sp[1] = ws[256];             // alpha
    __syncthreads();

    unsigned lo = (unsigned)lt;
    float a[8][8];
    #pragma unroll
    for (int i = 0; i < 8; ++i) {
        bool bi = ((lo >> i) & 1u) != 0u;
        #pragma unroll
        for (int j = 0; j < 8; ++j) {
            bool bj = ((lo >> j) & 1u) != 0u;
            a[i][j] = (bi && bj) ? s8[i * 8 + j] : ((i == j) ? 1.f : 0.f);
        }
    }

    float ld = sp[0] - sp[1];                  // partial - alpha
    #pragma unroll
    for (int k = 0; k < 8; ++k) {
        float piv = a[k][k];
        ld += __logf(fabsf(piv));
        float inv = 1.0f / piv;
        #pragma unroll
        for (int i = k + 1; i < 8; ++i) {
            float f = a[i][k] * inv;
            #pragma unroll
            for (int j = k + 1; j < 8; ++j)
                a[i][j] = fmaf(-f, a[k][j], a[i][j]);
        }
    }

    T[b * 256 + lt] = ld;                      // mask = (b<<8) | lt
}

__global__ __launch_bounds__(256) void main_kernel(const int4* __restrict__ x,
                                                   const float* __restrict__ ws,
                                                   float* __restrict__ out) {
    __shared__ float slw[256];
    int lt = threadIdx.x;
    slw[lt] = ws[lt];
    __syncthreads();

    int b = blockIdx.x * 256 + lt;
    const int4* xb = x + (size_t)b * 16;

    float lw = 0.f;
    unsigned mask = 0;
    #pragma unroll
    for (int j = 0; j < 16; ++j) {
        int4 v = xb[j];                              // 4 bits of part j
        int idx = v.x + 2 * v.y + 4 * v.z + 8 * v.w; // 0..15
        lw += slw[j * 16 + idx];                     // logw[j][0]==0
        mask |= (idx != 0 ? 1u : 0u) << j;
    }
    out[b] = lw + ws[32768 + mask];                  // T already has -alpha folded in
}

extern "C" void kernel_launch(void* const* d_in, const int* in_sizes, int n_in,
                              void* d_out, int out_size, void* d_ws, size_t ws_size,
                              hipStream_t stream) {
    const float* W = (const float*)d_in[1];
    const float* A = (const float*)d_in[2];
    const float* B = (const float*)d_in[3];
    const float* C = (const float*)d_in[4];
    const int4*  x = (const int4*)d_in[0];
    float* ws  = (float*)d_ws;
    float* out = (float*)d_out;

    stageA_kernel<<<5, 64, 0, stream>>>(W, A, B, C, ws);
    stageB_kernel<<<256, 256, 0, stream>>>(ws, ws + 32768);
    main_kernel<<<BATCH / 256, 256, 0, stream>>>(x, ws, out);
}